// Round 11
// baseline (1149.789 us; speedup 1.0000x reference)
//
#include <hip/hip_runtime.h>
#include <hip/hip_bf16.h>

typedef unsigned short u16;
typedef unsigned int   u32;
typedef unsigned long long u64;
typedef __attribute__((ext_vector_type(8))) short short8;
typedef __attribute__((ext_vector_type(4))) float f32x4;

#define HID   4096
#define NHEAD 32
#define HD    128
#define NB    4
#define NSQ   2048
#define NSK   128
#define MROWS (NB*NSQ)   // 8192
#define KROWS (NB*NSK)   // 512

// ---------- helpers ----------
__device__ __forceinline__ u16 f2bf(float f) {           // RNE f32->bf16 (finite data)
  u32 u = __builtin_bit_cast(u32, f);
  u += 0x7fffu + ((u >> 16) & 1u);
  return (u16)(u >> 16);
}

__device__ __forceinline__ float bf2f(u16 x) {
  u32 u = (u32)x << 16;
  return __builtin_bit_cast(float, u);
}

__device__ __forceinline__ u64 pack4(float4 f) {
  return (u64)f2bf(f.x) | ((u64)f2bf(f.y) << 16) |
         ((u64)f2bf(f.z) << 32) | ((u64)f2bf(f.w) << 48);
}

__device__ __forceinline__ uint4 packu16x8(const u16* v) {
  uint4 o;
  o.x = (u32)v[0] | ((u32)v[1] << 16);
  o.y = (u32)v[2] | ((u32)v[3] << 16);
  o.z = (u32)v[4] | ((u32)v[5] << 16);
  o.w = (u32)v[6] | ((u32)v[7] << 16);
  return o;
}

__device__ __forceinline__ f32x4 mfma16(short8 a, short8 b, f32x4 c) {
  return __builtin_amdgcn_mfma_f32_16x16x32_bf16(a, b, c, 0, 0, 0);
}

__device__ __forceinline__ void gload_lds16(const u16* g, u16* l) {
  __builtin_amdgcn_global_load_lds((const __attribute__((address_space(1))) u32*)g,
                                   (__attribute__((address_space(3))) u32*)l, 16, 0, 0);
}

// ---------- elementwise f32 -> bf16 (two tensors per launch) ----------
__global__ __launch_bounds__(256) void convert_bf16_x2(const float* __restrict__ in0,
                                                       u16* __restrict__ out0,
                                                       const float* __restrict__ in1,
                                                       u16* __restrict__ out1, long long n4)
{
  const float* in = blockIdx.y ? in1 : in0;
  u16* out = blockIdx.y ? out1 : out0;
  long long i = (long long)blockIdx.x * blockDim.x + threadIdx.x;
  const long long stride = (long long)gridDim.x * blockDim.x;
  for (; i < n4; i += stride) {
    float4 f = ((const float4*)in)[i];
    ((u64*)out)[i] = pack4(f);
  }
}

// ---------- W transpose + convert (four weights per launch): Wt[n][k] = bf16(W[k][n]) ----------
__global__ __launch_bounds__(256) void transpose_convert_x4(const float* __restrict__ W0, u16* __restrict__ T0,
                                                            const float* __restrict__ W1, u16* __restrict__ T1,
                                                            const float* __restrict__ W2, u16* __restrict__ T2,
                                                            const float* __restrict__ W3, u16* __restrict__ T3)
{
  const int z = blockIdx.z;
  const float* W = (z == 0) ? W0 : (z == 1) ? W1 : (z == 2) ? W2 : W3;
  u16* Wt = (z == 0) ? T0 : (z == 1) ? T1 : (z == 2) ? T2 : T3;
  __shared__ __align__(16) u16 tile[64][72];
  const int t = threadIdx.x;
  const int c0 = blockIdx.x * 64, r0 = blockIdx.y * 64;
  #pragma unroll
  for (int i = 0; i < 4; ++i) {
    int e = i * 1024 + t * 4;
    int rr = e >> 6, cc = e & 63;
    float4 f = *(const float4*)(W + (size_t)(r0 + rr) * HID + c0 + cc);
    *(u64*)&tile[rr][cc] = pack4(f);
  }
  __syncthreads();
  #pragma unroll
  for (int i = 0; i < 2; ++i) {
    int e = i * 2048 + t * 8;
    int cc = e >> 6, rr = e & 63;
    u16 vals[8];
    #pragma unroll
    for (int jj = 0; jj < 8; ++jj) vals[jj] = tile[rr + jj][cc];
    *(uint4*)(Wt + (size_t)(c0 + cc) * HID + r0 + rr) = packu16x8(vals);
  }
}

// ---------- per-head transpose of Vh ----------
__global__ __launch_bounds__(256) void transpose_head(const u16* __restrict__ Vh,
                                                      u16* __restrict__ VT)
{
  __shared__ __align__(16) u16 tile[128][136];
  const int t = threadIdx.x;
  const int bh = blockIdx.x;
  const int b = bh >> 5, h = bh & 31;
  #pragma unroll
  for (int i = 0; i < 8; ++i) {
    int e = i * 2048 + t * 8;
    int tr = e >> 7, d = e & 127;
    *(uint4*)&tile[tr][d] = *(const uint4*)(Vh + ((size_t)b * NSK + tr) * HID + h * HD + d);
  }
  __syncthreads();
  #pragma unroll
  for (int i = 0; i < 8; ++i) {
    int e = i * 2048 + t * 8;
    int d = e >> 7, tt = e & 127;
    u16 vals[8];
    #pragma unroll
    for (int jj = 0; jj < 8; ++jj) vals[jj] = tile[tt + jj][d];
    *(uint4*)(VT + ((size_t)bh * HD + d) * NSK + tt) = packu16x8(vals);
  }
}

// ====================== 256x256 GEMM, TWO fat phases per K-tile (R9 champion) ======================
// 8 waves (2Mx4N), BK=64, 128KB LDS dbuf, slot-XOR swizzle, 16x16x32 MFMA.
// P1: stage T+1-hi (issued first for max latency cover; targets other buffer,
//     dead >=2 barriers) + 16 ds_reads (A-lo + B all) -> lgkm(8) -> barrier ->
//     lgkm0 -> 32 MFMA (Mlo).
// P2: 8 ds_reads (A-hi) + stage T+2-lo into cur (after reads; write-after-read
//     margin ~500cy) -> vmcnt(4) -> barrier -> lgkm0 -> 32 MFMA (Mhi).

__device__ __forceinline__ short8 ldf(const u16* buf, int r, int cb) {
  return *(const short8*)(buf + r * 64 + (cb ^ ((r & 7) << 3)));
}

__device__ __forceinline__ void stage2(u16* dst, const u16* g, long off0, long off1, int tid) {
  gload_lds16(g + off0, dst + tid * 8);
  gload_lds16(g + off1, dst + 4096 + tid * 8);
}

template<int VM, bool S1, bool S2>
__device__ __forceinline__ void tile2(const u16* __restrict__ Ag, const u16* __restrict__ Bg,
                                      int kt, u16* Ac, u16* Bc, u16* Ao, u16* Bo,
                                      int wm, int wn, int g, int c16,
                                      long off0, long off1, int tid, f32x4 (&acc)[8][4])
{
  const int g8 = g * 8;
  short8 af[4][2], bf[4][2];

  // ---- P1: stage T+1-hi first, then A-lo (8 reads) + B all (8 reads) ----
  if constexpr (S1) {
    stage2(Ao + 8192, Ag + (size_t)128 * HID + kt + 64, off0, off1, tid);
    stage2(Bo + 8192, Bg + (size_t)128 * HID + kt + 64, off0, off1, tid);
  }
  #pragma unroll
  for (int i = 0; i < 4; ++i) {
    const int r = wm * 128 + i * 16 + c16;
    af[i][0] = ldf(Ac, r, g8); af[i][1] = ldf(Ac, r, 32 + g8);
  }
  #pragma unroll
  for (int j = 0; j < 4; ++j) {
    const int r = wn * 64 + j * 16 + c16;
    bf[j][0] = ldf(Bc, r, g8); bf[j][1] = ldf(Bc, r, 32 + g8);
  }
  asm volatile("s_waitcnt lgkmcnt(8)" ::: "memory");   // cap in-flight on 16-read phase
  __builtin_amdgcn_s_barrier();
  asm volatile("s_waitcnt lgkmcnt(0)" ::: "memory");
  __builtin_amdgcn_sched_barrier(0);
  __builtin_amdgcn_s_setprio(1);
  #pragma unroll
  for (int i = 0; i < 4; ++i)
    #pragma unroll
    for (int j = 0; j < 4; ++j)
      acc[i][j] = mfma16(af[i][0], bf[j][0], acc[i][j]);
  #pragma unroll
  for (int i = 0; i < 4; ++i)
    #pragma unroll
    for (int j = 0; j < 4; ++j)
      acc[i][j] = mfma16(af[i][1], bf[j][1], acc[i][j]);
  __builtin_amdgcn_s_setprio(0);

  // ---- P2: A-hi (8 reads); stage T+2-lo (B then A) into cur; counted vmcnt ----
  #pragma unroll
  for (int i = 0; i < 4; ++i) {
    const int r = wm * 128 + 64 + i * 16 + c16;
    af[i][0] = ldf(Ac, r, g8); af[i][1] = ldf(Ac, r, 32 + g8);
  }
  if constexpr (S2) {
    stage2(Bc, Bg + kt + 128, off0, off1, tid);
    stage2(Ac, Ag + kt + 128, off0, off1, tid);
  }
  if constexpr (VM == 4) {
    asm volatile("s_waitcnt vmcnt(4)" ::: "memory");
  } else if constexpr (VM == 0) {
    asm volatile("s_waitcnt vmcnt(0)" ::: "memory");
  }
  __builtin_amdgcn_s_barrier();
  asm volatile("s_waitcnt lgkmcnt(0)" ::: "memory");
  __builtin_amdgcn_sched_barrier(0);
  __builtin_amdgcn_s_setprio(1);
  #pragma unroll
  for (int i = 0; i < 4; ++i)
    #pragma unroll
    for (int j = 0; j < 4; ++j)
      acc[4 + i][j] = mfma16(af[i][0], bf[j][0], acc[4 + i][j]);
  #pragma unroll
  for (int i = 0; i < 4; ++i)
    #pragma unroll
    for (int j = 0; j < 4; ++j)
      acc[4 + i][j] = mfma16(af[i][1], bf[j][1], acc[4 + i][j]);
  __builtin_amdgcn_s_setprio(0);
}

// K-loop + epilogue shared by both GEMM kernels.
template<bool OUTF32>
__device__ __forceinline__ void gemm_body(const u16* __restrict__ Ag,
                                          const u16* __restrict__ Bg,
                                          u16* __restrict__ Ch, float* __restrict__ Cf,
                                          int n0, int tid,
                                          u16* As0, u16* As1, u16* Bs0, u16* Bs1)
{
  const int l = tid & 63, wv = tid >> 6;
  const int g = l >> 4 & 3, c16 = l & 15;
  const int wm = wv >> 2, wn = wv & 3;

  // per-thread staging source offsets (inverse slot-XOR swizzle)
  const long off0 = (long)(tid >> 3) * HID + (((tid & 7) ^ ((tid >> 3) & 7)) * 8);
  const long off1 = off0 + (long)64 * HID;

  f32x4 acc[8][4] = {};

  // prologue: Blo0, Alo0, Ahi0, Bhi0, Blo1, Alo1 ; vmcnt(4) -> tile0 landed
  stage2(Bs0,        Bg,                     off0, off1, tid);
  stage2(As0,        Ag,                     off0, off1, tid);
  stage2(As0 + 8192, Ag + (size_t)128 * HID, off0, off1, tid);
  stage2(Bs0 + 8192, Bg + (size_t)128 * HID, off0, off1, tid);
  stage2(Bs1,        Bg + 64,                off0, off1, tid);
  stage2(As1,        Ag + 64,                off0, off1, tid);
  asm volatile("s_waitcnt vmcnt(4)" ::: "memory");
  __builtin_amdgcn_sched_barrier(0);
  __builtin_amdgcn_s_barrier();

  constexpr int NT = HID / 64;   // 64
  for (int T = 0; T < NT - 3; T += 2) {
    tile2<4, true, true>(Ag, Bg, T * 64,      As0, Bs0, As1, Bs1,
                         wm, wn, g, c16, off0, off1, tid, acc);
    tile2<4, true, true>(Ag, Bg, T * 64 + 64, As1, Bs1, As0, Bs0,
                         wm, wn, g, c16, off0, off1, tid, acc);
  }
  tile2<0, true, false>(Ag, Bg, (NT - 2) * 64, As0, Bs0, As1, Bs1,
                        wm, wn, g, c16, off0, off1, tid, acc);
  tile2<-1, false, false>(Ag, Bg, (NT - 1) * 64, As1, Bs1, As0, Bs0,
                          wm, wn, g, c16, off0, off1, tid, acc);

  #pragma unroll
  for (int mi = 0; mi < 8; ++mi)
    #pragma unroll
    for (int j = 0; j < 4; ++j)
      #pragma unroll
      for (int rr = 0; rr < 4; ++rr) {
        const size_t idx = (size_t)(wm * 128 + mi * 16 + g * 4 + rr) * HID
                         + n0 + wn * 64 + j * 16 + c16;
        if constexpr (OUTF32) Cf[idx] = acc[mi][j][rr];
        else                  Ch[idx] = f2bf(acc[mi][j][rr]);
      }
}

// Merged projections: blocks [0,nQ) -> Qh = qb@WqT; [nQ,nQ+nR) -> Rhb = rb@WoT;
// rest -> Kh/Vh = kvb@WkT/WvT. All bf16 outputs.
__global__ __launch_bounds__(512, 2) void gemm_mega(const u16* __restrict__ qb,
                                                    const u16* __restrict__ WqT,
                                                    u16* __restrict__ Qh,
                                                    const u16* __restrict__ rb,
                                                    const u16* __restrict__ WoT,
                                                    u16* __restrict__ Rhb,
                                                    const u16* __restrict__ kvb,
                                                    const u16* __restrict__ WkT,
                                                    const u16* __restrict__ WvT,
                                                    u16* __restrict__ Kh,
                                                    u16* __restrict__ Vh,
                                                    int nQ, int nR)
{
  __shared__ __align__(16) u16 As[2][16384];
  __shared__ __align__(16) u16 Bs[2][16384];
  const int tid = threadIdx.x;

  const int nwg = gridDim.x;
  int wg = blockIdx.x;
  wg = (wg & 7) * (nwg >> 3) + (wg >> 3);          // bijective XCD swizzle (nwg%8==0)

  const u16* Ag; const u16* Bg; u16* Ch; int n0;
  if (wg < nQ) {
    const int m0 = (wg >> 4) * 256; n0 = (wg & 15) * 256;
    Ag = qb + (size_t)m0 * HID;  Bg = WqT + (size_t)n0 * HID;  Ch = Qh + (size_t)m0 * HID;
  } else if (wg < nQ + nR) {
    const int e = wg - nQ;
    const int m0 = (e >> 4) * 256; n0 = (e & 15) * 256;
    Ag = rb + (size_t)m0 * HID;  Bg = WoT + (size_t)n0 * HID;  Ch = Rhb + (size_t)m0 * HID;
  } else {
    const int e = wg - nQ - nR, mt = e >> 4;
    n0 = (e & 15) * 256;
    Ag = kvb + (size_t)(mt << 8) * HID;            // kb rows [0,512), vb rows [512,1024)
    Bg = (mt < 2 ? WkT : WvT) + (size_t)n0 * HID;
    Ch = (mt < 2 ? Kh : Vh) + (size_t)((mt & 1) << 8) * HID;
  }

  gemm_body<false>(Ag, Bg, Ch, nullptr, n0, tid, &As[0][0], &As[1][0], &Bs[0][0], &Bs[1][0]);
}

// Plain GEMM (f32 out) for the final projection.
__global__ __launch_bounds__(512, 2) void gemm256f(const u16* __restrict__ A,
                                                   const u16* __restrict__ Bt,
                                                   float* __restrict__ C)
{
  __shared__ __align__(16) u16 As[2][16384];
  __shared__ __align__(16) u16 Bs[2][16384];
  const int tid = threadIdx.x;

  const int nwg = gridDim.x;
  int wg = blockIdx.x;
  wg = (wg & 7) * (nwg >> 3) + (wg >> 3);
  const int m0 = (wg >> 4) * 256, n0 = (wg & 15) * 256;

  gemm_body<true>(A + (size_t)m0 * HID, Bt + (size_t)n0 * HID,
                  nullptr, C + (size_t)m0 * HID, n0, tid,
                  &As[0][0], &As[1][0], &Bs[0][0], &Bs[1][0]);
}

// ---------- fused attention (bias bf16, staged in LDS, overlapped with QK^T) ----------
__global__ __launch_bounds__(256) void attn_kernel(const u16*  __restrict__ Qh,
                                                   const u16*  __restrict__ Kh,
                                                   const u16*  __restrict__ VT,
                                                   const u16*  __restrict__ Rhb,
                                                   u16* __restrict__ ctx)
{
  __shared__ __align__(16) u16 sh[4][32][136];
  const int t = threadIdx.x;
  const int w = t >> 6, l = t & 63;
  const int g = l >> 4, c = l & 15;
  const int qc = blockIdx.x;
  const int bh = blockIdx.y;
  const int b = bh >> 5, h = bh & 31;
  const size_t qrow0 = (size_t)b * NSQ + qc * 128 + w * 32;
  const float SCALE = 0.08838834764831845f;  // 1/sqrt(128)

  // issue coalesced bias-tile loads; ds_writes land while QK^T computes
  const u16* brow = Rhb + ((size_t)b * NSQ + qc * 128) * HID + h * HD;
  #pragma unroll
  for (int it = 0; it < 8; ++it) {
    int e = it * 2048 + t * 8;
    int rr_ = e >> 7, cc = e & 127;
    *(uint4*)&sh[rr_ >> 5][rr_ & 31][cc] = *(const uint4*)(brow + (size_t)rr_ * HID + cc);
  }

  f32x4 s[2][8] = {};
  #pragma unroll
  for (int ks = 0; ks < 4; ++ks) {
    const int ko = ks * 32 + g * 8;
    short8 af[2];
    #pragma unroll
    for (int i = 0; i < 2; ++i)
      af[i] = *(const short8*)(Qh + (qrow0 + i * 16 + c) * HID + h * HD + ko);
    #pragma unroll
    for (int j = 0; j < 8; ++j) {
      short8 bfr = *(const short8*)(Kh + ((size_t)b * NSK + j * 16 + c) * HID + h * HD + ko);
      s[0][j] = mfma16(af[0], bfr, s[0][j]);
      s[1][j] = mfma16(af[1], bfr, s[1][j]);
    }
  }
  __syncthreads();   // bias tile fully staged

  float rinv[2][4];
  #pragma unroll
  for (int i = 0; i < 2; ++i) {
    #pragma unroll
    for (int rr = 0; rr < 4; ++rr) {
      const int lr = i * 16 + g * 4 + rr;
      float vmax = -3.0e38f;
      #pragma unroll
      for (int j = 0; j < 8; ++j) {
        float bias = bf2f(sh[w][lr][j * 16 + c]);
        float sv = s[i][j][rr] * SCALE + bias;
        s[i][j][rr] = sv;
        vmax = fmaxf(vmax, sv);
      }
      #pragma unroll
      for (int m = 1; m < 16; m <<= 1) vmax = fmaxf(vmax, __shfl_xor(vmax, m));
      float ssum = 0.f;
      #pragma unroll
      for (int j = 0; j < 8; ++j) {
        float p = __expf(s[i][j][rr] - vmax);
        s[i][j][rr] = p;
        ssum += p;
      }
      #pragma unroll
      for (int m = 1; m < 16; m <<= 1) ssum += __shfl_xor(ssum, m);
      rinv[i][rr] = 1.f / ssum;
    }
  }

  #pragma unroll
  for (int i = 0; i < 2; ++i)
    #pragma unroll
    for (int j = 0; j < 8; ++j)
      #pragma unroll
      for (int rr = 0; rr < 4; ++rr)
        sh[w][i * 16 + g * 4 + rr][j * 16 + c] = f2bf(s[i][j][rr]);
  __syncthreads();

  #pragma unroll
  for (int i = 0; i < 2; ++i) {
    f32x4 o[8] = {};
    #pragma unroll
    for (int ks = 0; ks < 4; ++ks) {
      const int ko = ks * 32 + g * 8;
      short8 pa = *(const short8*)(&sh[w][i * 16 + c][ko]);
      #pragma unroll
      for (int j = 0; j < 8; ++j) {
        short8 bv = *(const short8*)(VT + ((size_t)bh * HD + j * 16 + c) * NSK + ko);
        o[j] = mfma16(pa, bv, o[j]);
      }
    }
    #pragma unroll
    for (int j = 0; j < 8; ++j)
      #pragma unroll
      for (int rr = 0; rr < 4; ++rr) {
        const size_t row = qrow0 + i * 16 + g * 4 + rr;
        ctx[row * HID + h * HD + j * 16 + c] = f2bf(o[j][rr] * rinv[i][rr]);
      }
  }
}

// ---------- launch ----------
extern "C" void kernel_launch(void* const* d_in, const int* in_sizes, int n_in,
                              void* d_out, int out_size, void* d_ws, size_t ws_size,
                              hipStream_t stream)
{
  const float* q  = (const float*)d_in[0];
  const float* k  = (const float*)d_in[1];
  const float* v  = (const float*)d_in[2];
  const float* r  = (const float*)d_in[3];
  const float* Wq = (const float*)d_in[4];
  const float* Wk = (const float*)d_in[5];
  const float* Wv = (const float*)d_in[6];
  const float* Wo = (const float*)d_in[7];
  float* out = (float*)d_out;

  // ws: WoT[0,32) Qh[32,96) Kh[96,100) Vh[100,104) VT[104,108)
  //     rb/ctx[108,172)  Sb[172,236) (q-bf16, then Rh-bf16)  WqT[236,268)
  // d_out scratch: WkT[0,32) WvT[32,64) kvb[64,72) — consumed by the fused
  //                GEMM; d_out untouched after until the final GEMM.
  char* ws = (char*)d_ws;
  #define WSMB(x) ((size_t)(x) << 20)
  u16* WoT = (u16*)(ws + WSMB(0));
  u16* Qh  = (u16*)(ws + WSMB(32));
  u16* Kh  = (u16*)(ws + WSMB(96));
  u16* Vh  = (u16*)(ws + WSMB(100));
  u16* VTb = (u16*)(ws + WSMB(104));
  u16* rb  = (u16*)(ws + WSMB(108));
  u16* ctx = (u16*)(ws + WSMB(108));
  u16* Sb  = (u16*)(ws + WSMB(172));
  u16* WqT = (u16*)(ws + WSMB(236));
  u16* WkT = (u16*)((char*)d_out + WSMB(0));
  u16* WvT = (u16*)((char*)d_out + WSMB(32));
  u16* kvb = (u16*)((char*)d_out + WSMB(64));
  u16* vbp = kvb + (size_t)KROWS * HID;
  const size_t needed = WSMB(268);
  if (ws_size < needed) return;

  dim3 tb(256);
  dim3 tb5(512);
  const long long nBig = (long long)MROWS * HID / 4;
  const long long nSm  = (long long)KROWS * HID / 4;

  transpose_convert_x4<<<dim3(64, 64, 4), tb, 0, stream>>>(Wo, WoT, Wq, WqT, Wk, WkT, Wv, WvT);
  convert_bf16_x2<<<dim3(512, 2), tb, 0, stream>>>(k, kvb, v, vbp, nSm);
  convert_bf16_x2<<<dim3(2048, 2), tb, 0, stream>>>(q, Sb, r, rb, nBig);

  // Qh + KV (576 blocks), then Rh -> Sb (512 blocks; Sb's q-bf16 is dead)
  gemm_mega<<<dim3(576), tb5, 0, stream>>>(Sb, WqT, Qh, nullptr, nullptr, nullptr,
                                           kvb, WkT, WvT, Kh, Vh, 512, 0);
  gemm_mega<<<dim3(512), tb5, 0, stream>>>(nullptr, nullptr, nullptr, rb, WoT, Sb,
                                           nullptr, nullptr, nullptr, nullptr, nullptr, 0, 512);

  transpose_head<<<dim3(128), tb, 0, stream>>>(Vh, VTb);

  attn_kernel<<<dim3(16, 128), tb, 0, stream>>>(Qh, Kh, VTb, Sb, ctx);

  // out = ctx @ WoT (f32, overwrites all of d_out)
  gemm256f<<<dim3(512), tb5, 0, stream>>>(ctx, WoT, out);
}

// Round 12
// 999.628 us; speedup vs baseline: 1.1502x; 1.1502x over previous
//
#include <hip/hip_runtime.h>
#include <hip/hip_bf16.h>

typedef unsigned short u16;
typedef unsigned int   u32;
typedef unsigned long long u64;
typedef __attribute__((ext_vector_type(8))) short short8;
typedef __attribute__((ext_vector_type(4))) float f32x4;

#define HID   4096
#define NHEAD 32
#define HD    128
#define NB    4
#define NSQ   2048
#define NSK   128
#define MROWS (NB*NSQ)   // 8192
#define KROWS (NB*NSK)   // 512

// ---------- helpers ----------
__device__ __forceinline__ u16 f2bf(float f) {           // RNE f32->bf16 (finite data)
  u32 u = __builtin_bit_cast(u32, f);
  u += 0x7fffu + ((u >> 16) & 1u);
  return (u16)(u >> 16);
}

__device__ __forceinline__ float bf2f(u16 x) {
  u32 u = (u32)x << 16;
  return __builtin_bit_cast(float, u);
}

__device__ __forceinline__ u64 pack4(float4 f) {
  return (u64)f2bf(f.x) | ((u64)f2bf(f.y) << 16) |
         ((u64)f2bf(f.z) << 32) | ((u64)f2bf(f.w) << 48);
}

__device__ __forceinline__ uint4 packu16x8(const u16* v) {
  uint4 o;
  o.x = (u32)v[0] | ((u32)v[1] << 16);
  o.y = (u32)v[2] | ((u32)v[3] << 16);
  o.z = (u32)v[4] | ((u32)v[5] << 16);
  o.w = (u32)v[6] | ((u32)v[7] << 16);
  return o;
}

__device__ __forceinline__ f32x4 mfma16(short8 a, short8 b, f32x4 c) {
  return __builtin_amdgcn_mfma_f32_16x16x32_bf16(a, b, c, 0, 0, 0);
}

__device__ __forceinline__ void gload_lds16(const u16* g, u16* l) {
  __builtin_amdgcn_global_load_lds((const __attribute__((address_space(1))) u32*)g,
                                   (__attribute__((address_space(3))) u32*)l, 16, 0, 0);
}

// ---------- elementwise f32 -> bf16 (two tensors per launch) ----------
__global__ __launch_bounds__(256) void convert_bf16_x2(const float* __restrict__ in0,
                                                       u16* __restrict__ out0,
                                                       const float* __restrict__ in1,
                                                       u16* __restrict__ out1, long long n4)
{
  const float* in = blockIdx.y ? in1 : in0;
  u16* out = blockIdx.y ? out1 : out0;
  long long i = (long long)blockIdx.x * blockDim.x + threadIdx.x;
  const long long stride = (long long)gridDim.x * blockDim.x;
  for (; i < n4; i += stride) {
    float4 f = ((const float4*)in)[i];
    ((u64*)out)[i] = pack4(f);
  }
}

// ---------- W transpose + convert (four weights per launch): Wt[n][k] = bf16(W[k][n]) ----------
__global__ __launch_bounds__(256) void transpose_convert_x4(const float* __restrict__ W0, u16* __restrict__ T0,
                                                            const float* __restrict__ W1, u16* __restrict__ T1,
                                                            const float* __restrict__ W2, u16* __restrict__ T2,
                                                            const float* __restrict__ W3, u16* __restrict__ T3)
{
  const int z = blockIdx.z;
  const float* W = (z == 0) ? W0 : (z == 1) ? W1 : (z == 2) ? W2 : W3;
  u16* Wt = (z == 0) ? T0 : (z == 1) ? T1 : (z == 2) ? T2 : T3;
  __shared__ __align__(16) u16 tile[64][72];
  const int t = threadIdx.x;
  const int c0 = blockIdx.x * 64, r0 = blockIdx.y * 64;
  #pragma unroll
  for (int i = 0; i < 4; ++i) {
    int e = i * 1024 + t * 4;
    int rr = e >> 6, cc = e & 63;
    float4 f = *(const float4*)(W + (size_t)(r0 + rr) * HID + c0 + cc);
    *(u64*)&tile[rr][cc] = pack4(f);
  }
  __syncthreads();
  #pragma unroll
  for (int i = 0; i < 2; ++i) {
    int e = i * 2048 + t * 8;
    int cc = e >> 6, rr = e & 63;
    u16 vals[8];
    #pragma unroll
    for (int jj = 0; jj < 8; ++jj) vals[jj] = tile[rr + jj][cc];
    *(uint4*)(Wt + (size_t)(c0 + cc) * HID + r0 + rr) = packu16x8(vals);
  }
}

// ---------- per-head transpose of Vh ----------
__global__ __launch_bounds__(256) void transpose_head(const u16* __restrict__ Vh,
                                                      u16* __restrict__ VT)
{
  __shared__ __align__(16) u16 tile[128][136];
  const int t = threadIdx.x;
  const int bh = blockIdx.x;
  const int b = bh >> 5, h = bh & 31;
  #pragma unroll
  for (int i = 0; i < 8; ++i) {
    int e = i * 2048 + t * 8;
    int tr = e >> 7, d = e & 127;
    *(uint4*)&tile[tr][d] = *(const uint4*)(Vh + ((size_t)b * NSK + tr) * HID + h * HD + d);
  }
  __syncthreads();
  #pragma unroll
  for (int i = 0; i < 8; ++i) {
    int e = i * 2048 + t * 8;
    int d = e >> 7, tt = e & 127;
    u16 vals[8];
    #pragma unroll
    for (int jj = 0; jj < 8; ++jj) vals[jj] = tile[tt + jj][d];
    *(uint4*)(VT + ((size_t)bh * HD + d) * NSK + tt) = packu16x8(vals);
  }
}

// ====================== 256x256 GEMM, TWO fat phases per K-tile (R9 champion) ======================
// 8 waves (2Mx4N), BK=64, 128KB LDS dbuf, slot-XOR swizzle, 16x16x32 MFMA.
// P1: 16 ds_reads FIRST (A-lo + B all; issue-critical), then stage T+1-hi ->
//     lgkm(8) -> barrier -> lgkm0 -> 32 MFMA (Mlo).
// P2: 8 ds_reads (A-hi), then stage T+2-lo into cur -> vmcnt(4) -> barrier ->
//     lgkm0 -> 32 MFMA (Mhi).  (R11 lesson: reads before stages, always.)

__device__ __forceinline__ short8 ldf(const u16* buf, int r, int cb) {
  return *(const short8*)(buf + r * 64 + (cb ^ ((r & 7) << 3)));
}

__device__ __forceinline__ void stage2(u16* dst, const u16* g, long off0, long off1, int tid) {
  gload_lds16(g + off0, dst + tid * 8);
  gload_lds16(g + off1, dst + 4096 + tid * 8);
}

template<int VM, bool S1, bool S2>
__device__ __forceinline__ void tile2(const u16* __restrict__ Ag, const u16* __restrict__ Bg,
                                      int kt, u16* Ac, u16* Bc, u16* Ao, u16* Bo,
                                      int wm, int wn, int g, int c16,
                                      long off0, long off1, int tid, f32x4 (&acc)[8][4])
{
  const int g8 = g * 8;
  short8 af[4][2], bf[4][2];

  // ---- P1: A-lo (8 reads) + B all (8 reads); stage T+1-hi (A then B) ----
  #pragma unroll
  for (int i = 0; i < 4; ++i) {
    const int r = wm * 128 + i * 16 + c16;
    af[i][0] = ldf(Ac, r, g8); af[i][1] = ldf(Ac, r, 32 + g8);
  }
  #pragma unroll
  for (int j = 0; j < 4; ++j) {
    const int r = wn * 64 + j * 16 + c16;
    bf[j][0] = ldf(Bc, r, g8); bf[j][1] = ldf(Bc, r, 32 + g8);
  }
  if constexpr (S1) {
    stage2(Ao + 8192, Ag + (size_t)128 * HID + kt + 64, off0, off1, tid);
    stage2(Bo + 8192, Bg + (size_t)128 * HID + kt + 64, off0, off1, tid);
  }
  asm volatile("s_waitcnt lgkmcnt(8)" ::: "memory");   // cap in-flight on 16-read phase
  __builtin_amdgcn_s_barrier();
  asm volatile("s_waitcnt lgkmcnt(0)" ::: "memory");
  __builtin_amdgcn_sched_barrier(0);
  __builtin_amdgcn_s_setprio(1);
  #pragma unroll
  for (int i = 0; i < 4; ++i)
    #pragma unroll
    for (int j = 0; j < 4; ++j)
      acc[i][j] = mfma16(af[i][0], bf[j][0], acc[i][j]);
  #pragma unroll
  for (int i = 0; i < 4; ++i)
    #pragma unroll
    for (int j = 0; j < 4; ++j)
      acc[i][j] = mfma16(af[i][1], bf[j][1], acc[i][j]);
  __builtin_amdgcn_s_setprio(0);

  // ---- P2: A-hi (8 reads); stage T+2-lo (B then A) into cur; counted vmcnt ----
  #pragma unroll
  for (int i = 0; i < 4; ++i) {
    const int r = wm * 128 + 64 + i * 16 + c16;
    af[i][0] = ldf(Ac, r, g8); af[i][1] = ldf(Ac, r, 32 + g8);
  }
  if constexpr (S2) {
    stage2(Bc, Bg + kt + 128, off0, off1, tid);
    stage2(Ac, Ag + kt + 128, off0, off1, tid);
  }
  if constexpr (VM == 4) {
    asm volatile("s_waitcnt vmcnt(4)" ::: "memory");
  } else if constexpr (VM == 0) {
    asm volatile("s_waitcnt vmcnt(0)" ::: "memory");
  }
  __builtin_amdgcn_s_barrier();
  asm volatile("s_waitcnt lgkmcnt(0)" ::: "memory");
  __builtin_amdgcn_sched_barrier(0);
  __builtin_amdgcn_s_setprio(1);
  #pragma unroll
  for (int i = 0; i < 4; ++i)
    #pragma unroll
    for (int j = 0; j < 4; ++j)
      acc[4 + i][j] = mfma16(af[i][0], bf[j][0], acc[4 + i][j]);
  #pragma unroll
  for (int i = 0; i < 4; ++i)
    #pragma unroll
    for (int j = 0; j < 4; ++j)
      acc[4 + i][j] = mfma16(af[i][1], bf[j][1], acc[4 + i][j]);
  __builtin_amdgcn_s_setprio(0);
}

// K-loop + epilogue shared by both GEMM kernels.
template<bool OUTF32>
__device__ __forceinline__ void gemm_body(const u16* __restrict__ Ag,
                                          const u16* __restrict__ Bg,
                                          u16* __restrict__ Ch, float* __restrict__ Cf,
                                          int n0, int tid,
                                          u16* As0, u16* As1, u16* Bs0, u16* Bs1)
{
  const int l = tid & 63, wv = tid >> 6;
  const int g = l >> 4 & 3, c16 = l & 15;
  const int wm = wv >> 2, wn = wv & 3;

  // per-thread staging source offsets (inverse slot-XOR swizzle)
  const long off0 = (long)(tid >> 3) * HID + (((tid & 7) ^ ((tid >> 3) & 7)) * 8);
  const long off1 = off0 + (long)64 * HID;

  f32x4 acc[8][4] = {};

  // prologue: Blo0, Alo0, Ahi0, Bhi0, Blo1, Alo1 ; vmcnt(4) -> tile0 landed
  stage2(Bs0,        Bg,                     off0, off1, tid);
  stage2(As0,        Ag,                     off0, off1, tid);
  stage2(As0 + 8192, Ag + (size_t)128 * HID, off0, off1, tid);
  stage2(Bs0 + 8192, Bg + (size_t)128 * HID, off0, off1, tid);
  stage2(Bs1,        Bg + 64,                off0, off1, tid);
  stage2(As1,        Ag + 64,                off0, off1, tid);
  asm volatile("s_waitcnt vmcnt(4)" ::: "memory");
  __builtin_amdgcn_sched_barrier(0);
  __builtin_amdgcn_s_barrier();

  constexpr int NT = HID / 64;   // 64
  for (int T = 0; T < NT - 3; T += 2) {
    tile2<4, true, true>(Ag, Bg, T * 64,      As0, Bs0, As1, Bs1,
                         wm, wn, g, c16, off0, off1, tid, acc);
    tile2<4, true, true>(Ag, Bg, T * 64 + 64, As1, Bs1, As0, Bs0,
                         wm, wn, g, c16, off0, off1, tid, acc);
  }
  tile2<0, true, false>(Ag, Bg, (NT - 2) * 64, As0, Bs0, As1, Bs1,
                        wm, wn, g, c16, off0, off1, tid, acc);
  tile2<-1, false, false>(Ag, Bg, (NT - 1) * 64, As1, Bs1, As0, Bs0,
                          wm, wn, g, c16, off0, off1, tid, acc);

  #pragma unroll
  for (int mi = 0; mi < 8; ++mi)
    #pragma unroll
    for (int j = 0; j < 4; ++j)
      #pragma unroll
      for (int rr = 0; rr < 4; ++rr) {
        const size_t idx = (size_t)(wm * 128 + mi * 16 + g * 4 + rr) * HID
                         + n0 + wn * 64 + j * 16 + c16;
        if constexpr (OUTF32) Cf[idx] = acc[mi][j][rr];
        else                  Ch[idx] = f2bf(acc[mi][j][rr]);
      }
}

// Merged projections: blocks [0,nQ) -> Qh = qb@WqT; [nQ,nQ+nR) -> Rhb = rb@WoT;
// rest -> Kh/Vh = kvb@WkT/WvT. All bf16 outputs.
__global__ __launch_bounds__(512, 2) void gemm_mega(const u16* __restrict__ qb,
                                                    const u16* __restrict__ WqT,
                                                    u16* __restrict__ Qh,
                                                    const u16* __restrict__ rb,
                                                    const u16* __restrict__ WoT,
                                                    u16* __restrict__ Rhb,
                                                    const u16* __restrict__ kvb,
                                                    const u16* __restrict__ WkT,
                                                    const u16* __restrict__ WvT,
                                                    u16* __restrict__ Kh,
                                                    u16* __restrict__ Vh,
                                                    int nQ, int nR)
{
  __shared__ __align__(16) u16 As[2][16384];
  __shared__ __align__(16) u16 Bs[2][16384];
  const int tid = threadIdx.x;

  const int nwg = gridDim.x;
  int wg = blockIdx.x;
  wg = (wg & 7) * (nwg >> 3) + (wg >> 3);          // bijective XCD swizzle (nwg%8==0)

  const u16* Ag; const u16* Bg; u16* Ch; int n0;
  if (wg < nQ) {
    const int m0 = (wg >> 4) * 256; n0 = (wg & 15) * 256;
    Ag = qb + (size_t)m0 * HID;  Bg = WqT + (size_t)n0 * HID;  Ch = Qh + (size_t)m0 * HID;
  } else if (wg < nQ + nR) {
    const int e = wg - nQ;
    const int m0 = (e >> 4) * 256; n0 = (e & 15) * 256;
    Ag = rb + (size_t)m0 * HID;  Bg = WoT + (size_t)n0 * HID;  Ch = Rhb + (size_t)m0 * HID;
  } else {
    const int e = wg - nQ - nR, mt = e >> 4;
    n0 = (e & 15) * 256;
    Ag = kvb + (size_t)(mt << 8) * HID;            // kb rows [0,512), vb rows [512,1024)
    Bg = (mt < 2 ? WkT : WvT) + (size_t)n0 * HID;
    Ch = (mt < 2 ? Kh : Vh) + (size_t)((mt & 1) << 8) * HID;
  }

  gemm_body<false>(Ag, Bg, Ch, nullptr, n0, tid, &As[0][0], &As[1][0], &Bs[0][0], &Bs[1][0]);
}

// Plain GEMM (f32 out) for the final projection.
__global__ __launch_bounds__(512, 2) void gemm256f(const u16* __restrict__ A,
                                                   const u16* __restrict__ Bt,
                                                   float* __restrict__ C)
{
  __shared__ __align__(16) u16 As[2][16384];
  __shared__ __align__(16) u16 Bs[2][16384];
  const int tid = threadIdx.x;

  const int nwg = gridDim.x;
  int wg = blockIdx.x;
  wg = (wg & 7) * (nwg >> 3) + (wg >> 3);
  const int m0 = (wg >> 4) * 256, n0 = (wg & 15) * 256;

  gemm_body<true>(A + (size_t)m0 * HID, Bt + (size_t)n0 * HID,
                  nullptr, C + (size_t)m0 * HID, n0, tid,
                  &As[0][0], &As[1][0], &Bs[0][0], &Bs[1][0]);
}

// ---------- fused attention (bias bf16, staged in LDS, overlapped with QK^T) ----------
__global__ __launch_bounds__(256) void attn_kernel(const u16*  __restrict__ Qh,
                                                   const u16*  __restrict__ Kh,
                                                   const u16*  __restrict__ VT,
                                                   const u16*  __restrict__ Rhb,
                                                   u16* __restrict__ ctx)
{
  __shared__ __align__(16) u16 sh[4][32][136];
  const int t = threadIdx.x;
  const int w = t >> 6, l = t & 63;
  const int g = l >> 4, c = l & 15;
  const int qc = blockIdx.x;
  const int bh = blockIdx.y;
  const int b = bh >> 5, h = bh & 31;
  const size_t qrow0 = (size_t)b * NSQ + qc * 128 + w * 32;
  const float SCALE = 0.08838834764831845f;  // 1/sqrt(128)

  // issue coalesced bias-tile loads; ds_writes land while QK^T computes
  const u16* brow = Rhb + ((size_t)b * NSQ + qc * 128) * HID + h * HD;
  #pragma unroll
  for (int it = 0; it < 8; ++it) {
    int e = it * 2048 + t * 8;
    int rr_ = e >> 7, cc = e & 127;
    *(uint4*)&sh[rr_ >> 5][rr_ & 31][cc] = *(const uint4*)(brow + (size_t)rr_ * HID + cc);
  }

  f32x4 s[2][8] = {};
  #pragma unroll
  for (int ks = 0; ks < 4; ++ks) {
    const int ko = ks * 32 + g * 8;
    short8 af[2];
    #pragma unroll
    for (int i = 0; i < 2; ++i)
      af[i] = *(const short8*)(Qh + (qrow0 + i * 16 + c) * HID + h * HD + ko);
    #pragma unroll
    for (int j = 0; j < 8; ++j) {
      short8 bfr = *(const short8*)(Kh + ((size_t)b * NSK + j * 16 + c) * HID + h * HD + ko);
      s[0][j] = mfma16(af[0], bfr, s[0][j]);
      s[1][j] = mfma16(af[1], bfr, s[1][j]);
    }
  }
  __syncthreads();   // bias tile fully staged

  float rinv[2][4];
  #pragma unroll
  for (int i = 0; i < 2; ++i) {
    #pragma unroll
    for (int rr = 0; rr < 4; ++rr) {
      const int lr = i * 16 + g * 4 + rr;
      float vmax = -3.0e38f;
      #pragma unroll
      for (int j = 0; j < 8; ++j) {
        float bias = bf2f(sh[w][lr][j * 16 + c]);
        float sv = s[i][j][rr] * SCALE + bias;
        s[i][j][rr] = sv;
        vmax = fmaxf(vmax, sv);
      }
      #pragma unroll
      for (int m = 1; m < 16; m <<= 1) vmax = fmaxf(vmax, __shfl_xor(vmax, m));
      float ssum = 0.f;
      #pragma unroll
      for (int j = 0; j < 8; ++j) {
        float p = __expf(s[i][j][rr] - vmax);
        s[i][j][rr] = p;
        ssum += p;
      }
      #pragma unroll
      for (int m = 1; m < 16; m <<= 1) ssum += __shfl_xor(ssum, m);
      rinv[i][rr] = 1.f / ssum;
    }
  }

  #pragma unroll
  for (int i = 0; i < 2; ++i)
    #pragma unroll
    for (int j = 0; j < 8; ++j)
      #pragma unroll
      for (int rr = 0; rr < 4; ++rr)
        sh[w][i * 16 + g * 4 + rr][j * 16 + c] = f2bf(s[i][j][rr]);
  __syncthreads();

  #pragma unroll
  for (int i = 0; i < 2; ++i) {
    f32x4 o[8] = {};
    #pragma unroll
    for (int ks = 0; ks < 4; ++ks) {
      const int ko = ks * 32 + g * 8;
      short8 pa = *(const short8*)(&sh[w][i * 16 + c][ko]);
      #pragma unroll
      for (int j = 0; j < 8; ++j) {
        short8 bv = *(const short8*)(VT + ((size_t)bh * HD + j * 16 + c) * NSK + ko);
        o[j] = mfma16(pa, bv, o[j]);
      }
    }
    #pragma unroll
    for (int j = 0; j < 8; ++j)
      #pragma unroll
      for (int rr = 0; rr < 4; ++rr) {
        const size_t row = qrow0 + i * 16 + g * 4 + rr;
        ctx[row * HID + h * HD + j * 16 + c] = f2bf(o[j][rr] * rinv[i][rr]);
      }
  }
}

// ---------- launch ----------
extern "C" void kernel_launch(void* const* d_in, const int* in_sizes, int n_in,
                              void* d_out, int out_size, void* d_ws, size_t ws_size,
                              hipStream_t stream)
{
  const float* q  = (const float*)d_in[0];
  const float* k  = (const float*)d_in[1];
  const float* v  = (const float*)d_in[2];
  const float* r  = (const float*)d_in[3];
  const float* Wq = (const float*)d_in[4];
  const float* Wk = (const float*)d_in[5];
  const float* Wv = (const float*)d_in[6];
  const float* Wo = (const float*)d_in[7];
  float* out = (float*)d_out;

  // ws: WoT[0,32) Qh[32,96) Kh[96,100) Vh[100,104) VT[104,108)
  //     rb/ctx[108,172)  Sb[172,236) (q-bf16, then Rh-bf16)  WqT[236,268)
  // d_out scratch: WkT[0,32) WvT[32,64) kvb[64,72) — consumed by the fused
  //                GEMM; d_out untouched after until the final GEMM.
  char* ws = (char*)d_ws;
  #define WSMB(x) ((size_t)(x) << 20)
  u16* WoT = (u16*)(ws + WSMB(0));
  u16* Qh  = (u16*)(ws + WSMB(32));
  u16* Kh  = (u16*)(ws + WSMB(96));
  u16* Vh  = (u16*)(ws + WSMB(100));
  u16* VTb = (u16*)(ws + WSMB(104));
  u16* rb  = (u16*)(ws + WSMB(108));
  u16* ctx = (u16*)(ws + WSMB(108));
  u16* Sb  = (u16*)(ws + WSMB(172));
  u16* WqT = (u16*)(ws + WSMB(236));
  u16* WkT = (u16*)((char*)d_out + WSMB(0));
  u16* WvT = (u16*)((char*)d_out + WSMB(32));
  u16* kvb = (u16*)((char*)d_out + WSMB(64));
  u16* vbp = kvb + (size_t)KROWS * HID;
  const size_t needed = WSMB(268);
  if (ws_size < needed) return;

  dim3 tb(256);
  dim3 tb5(512);
  const long long nBig = (long long)MROWS * HID / 4;
  const long long nSm  = (long long)KROWS * HID / 4;

  transpose_convert_x4<<<dim3(64, 64, 4), tb, 0, stream>>>(Wo, WoT, Wq, WqT, Wk, WkT, Wv, WvT);
  convert_bf16_x2<<<dim3(512, 2), tb, 0, stream>>>(k, kvb, v, vbp, nSm);
  convert_bf16_x2<<<dim3(2048, 2), tb, 0, stream>>>(q, Sb, r, rb, nBig);

  // Qh + KV (576 blocks), then Rh -> Sb (512 blocks; Sb's q-bf16 is dead)
  gemm_mega<<<dim3(576), tb5, 0, stream>>>(Sb, WqT, Qh, nullptr, nullptr, nullptr,
                                           kvb, WkT, WvT, Kh, Vh, 512, 0);
  gemm_mega<<<dim3(512), tb5, 0, stream>>>(nullptr, nullptr, nullptr, rb, WoT, Sb,
                                           nullptr, nullptr, nullptr, nullptr, nullptr, 0, 512);

  transpose_head<<<dim3(128), tb, 0, stream>>>(Vh, VTb);

  attn_kernel<<<dim3(16, 128), tb, 0, stream>>>(Qh, Kh, VTb, Sb, ctx);

  // out = ctx @ WoT (f32, overwrites all of d_out)
  gemm256f<<<dim3(512), tb5, 0, stream>>>(ctx, WoT, out);
}